// Round 3
// baseline (580.486 us; speedup 1.0000x reference)
//
#include <hip/hip_runtime.h>
#include <hip/hip_bf16.h>
#include <stdint.h>

static constexpr int cN    = 4096;
static constexpr int cHID  = 256;
static constexpr int cTASK = 128;
static constexpr int cL    = 2;

typedef short bf16x8 __attribute__((ext_vector_type(8)));
typedef float f32x4  __attribute__((ext_vector_type(4)));

#define MFMA(a, b, c) __builtin_amdgcn_mfma_f32_16x16x32_bf16((a), (b), (c), 0, 0, 0)

static __device__ __forceinline__ uint16_t f2bf(float f) {
    uint32_t u = __float_as_uint(f);
    uint32_t r = (u + 0x7FFFu + ((u >> 16) & 1u)) >> 16;
    return (uint16_t)r;
}
static __device__ __forceinline__ float bf2f(uint16_t h) {
    return __uint_as_float(((uint32_t)h) << 16);
}
static __device__ __forceinline__ bf16x8 ld_frag(const uint16_t* p) {
    return *reinterpret_cast<const bf16x8*>(p);
}
// spread byte bits t -> bit 4t
static __device__ __forceinline__ uint32_t spread4(uint32_t x) {
    x = (x | (x << 12)) & 0x000F000Fu;
    x = (x | (x << 6))  & 0x03030303u;
    x = (x | (x << 3))  & 0x11111111u;
    return x;
}

// ---------------- merged prep: casts + weight transposes + attention-vector fold ----------------
static __device__ __forceinline__ void castT_body(const float* __restrict__ S,
                                                  uint16_t* __restrict__ D, int K, int bx,
                                                  uint16_t (*t)[72]) {
    int ntk = K / 64;
    int tk = (bx % ntk) * 64;
    int td = (bx / ntk) * 64;
    int lane = threadIdx.x & 63, w = threadIdx.x >> 6;
    for (int r = w; r < 64; r += 4) t[r][lane] = f2bf(S[(size_t)(tk + r) * 256 + td + lane]);
    __syncthreads();
    for (int r = w; r < 64; r += 4) D[(size_t)(td + r) * K + tk + lane] = t[lane][r];
}

__global__ __launch_bounds__(256) void k_prep(const float* __restrict__ h,
                                              const float* __restrict__ z,
                                              const float* __restrict__ Wp,
                                              const float* __restrict__ Wm,
                                              const float* __restrict__ Wg,
                                              const float* __restrict__ Wq,
                                              const float* __restrict__ bq,
                                              const float* __restrict__ Wk,
                                              const float* __restrict__ bk,
                                              const float* __restrict__ a,
                                              uint16_t* __restrict__ hin_bf,
                                              uint16_t* __restrict__ z_bf,
                                              uint16_t* __restrict__ WpT,
                                              uint16_t* __restrict__ WmT,
                                              uint16_t* __restrict__ WgT,
                                              float* __restrict__ wqv,
                                              float* __restrict__ wkv,
                                              float* __restrict__ cvec) {
    __shared__ uint16_t sht[64][72];
    __shared__ float shf[2][256];
    int b = blockIdx.x, tid = threadIdx.x;
    if (b < 1024) {                                    // h cast (vec4)
        int idx = b * 256 + tid;
        float4 v = reinterpret_cast<const float4*>(h)[idx];
        ushort4 o; o.x = f2bf(v.x); o.y = f2bf(v.y); o.z = f2bf(v.z); o.w = f2bf(v.w);
        reinterpret_cast<ushort4*>(hin_bf)[idx] = o;
        return;
    }
    b -= 1024;
    if (b < 512) {                                     // z cast (vec4)
        int idx = b * 256 + tid;
        float4 v = reinterpret_cast<const float4*>(z)[idx];
        ushort4 o; o.x = f2bf(v.x); o.y = f2bf(v.y); o.z = f2bf(v.z); o.w = f2bf(v.w);
        reinterpret_cast<ushort4*>(z_bf)[idx] = o;
        return;
    }
    b -= 512;
    if (b < 16) { castT_body(Wp, WpT, 256, b, sht); return; }
    b -= 16;
    if (b < 32) { castT_body(Wm + (b >> 4) * 65536, WmT + (b >> 4) * 65536, 256, b & 15, sht); return; }
    b -= 32;
    if (b < 48) { castT_body(Wg + (b / 24) * 98304, WgT + (b / 24) * 98304, 384, b % 24, sht); return; }
    b -= 48;
    {   // wvec: 16 blocks: l = b>>3, which = (b>>2)&1, q = b&3
        int l = b >> 3, which = (b >> 2) & 1, q = b & 3;
        int lane = tid & 63, wid = tid >> 6;
        const float* W    = which ? (Wk + l * 65536) : (Wq + l * 65536);
        const float* avec = a + l * 512 + (which ? 0 : 256);
        float* av = shf[0];
        float* red = shf[1];
        av[tid] = avec[tid];
        __syncthreads();
        float av0 = av[lane], av1 = av[64 + lane], av2 = av[128 + lane], av3 = av[192 + lane];
        float* wv = which ? wkv : wqv;
        for (int dd = 0; dd < 16; ++dd) {
            int d = q * 64 + wid * 16 + dd;
            const float* Wr = W + (size_t)d * 256;
            float s = Wr[lane] * av0 + Wr[64 + lane] * av1 + Wr[128 + lane] * av2 + Wr[192 + lane] * av3;
            for (int off = 32; off; off >>= 1) s += __shfl_down(s, off, 64);
            if (lane == 0) wv[l * 256 + d] = s;
        }
        if (q == 0) {
            const float* bias = which ? (bk + l * 256) : (bq + l * 256);
            red[tid] = bias[tid] * av[tid];
            __syncthreads();
            for (int off = 128; off; off >>= 1) {
                if (tid < off) red[tid] += red[tid + off];
                __syncthreads();
            }
            if (tid == 0) cvec[l * 2 + which] = red[0];
        }
    }
}

// ---------------- adj -> bitmask, int4 loads + ballot pack ----------------
__global__ __launch_bounds__(256) void k_bits(const int* __restrict__ adj,
                                              uint32_t* __restrict__ maskw) {
    int wid = threadIdx.x >> 6, lane = threadIdx.x & 63;
    int i = blockIdx.x * 4 + wid;
    const int* row = adj + (size_t)i * cN;
    uint32_t* orow = maskw + (size_t)i * 128;
    for (int ch = 0; ch < 16; ++ch) {
        int4 v = reinterpret_cast<const int4*>(row + ch * 256)[lane];
        uint64_t b0 = __ballot(v.x > 0);
        uint64_t b1 = __ballot(v.y > 0);
        uint64_t b2 = __ballot(v.z > 0);
        uint64_t b3 = __ballot(v.w > 0);
        int k = lane & 7;
        uint32_t e0 = spread4((uint32_t)(b0 >> (8 * k)) & 0xFFu);
        uint32_t e1 = spread4((uint32_t)(b1 >> (8 * k)) & 0xFFu);
        uint32_t e2 = spread4((uint32_t)(b2 >> (8 * k)) & 0xFFu);
        uint32_t e3 = spread4((uint32_t)(b3 >> (8 * k)) & 0xFFu);
        if (lane < 8) orow[ch * 8 + k] = e0 | (e1 << 1) | (e2 << 2) | (e3 << 3);
    }
}

// ---------------- initial projection: h = hin @ Wp + bp ----------------
__global__ __launch_bounds__(256) void k_proj(const uint16_t* __restrict__ hin_bf,
                                              const uint16_t* __restrict__ WpT,
                                              const float* __restrict__ bp,
                                              float* __restrict__ h_f32,
                                              uint16_t* __restrict__ hcur_bf) {
    int bx = blockIdx.x, by = blockIdx.y;
    int tid = threadIdx.x, lane = tid & 63, wid = tid >> 6;
    int wr = wid >> 1, wc = wid & 1;
    int l16 = lane & 15, g = lane >> 4;
    int i0 = bx * 64 + wr * 32, d0 = by * 64 + wc * 32;
    f32x4 acc[2][2] = {};
#pragma unroll
    for (int ks = 0; ks < 8; ++ks) {
        int kb = ks * 32 + g * 8;
        bf16x8 afr[2], bfr[2];
#pragma unroll
        for (int mr = 0; mr < 2; ++mr) afr[mr] = ld_frag(hin_bf + (size_t)(i0 + mr * 16 + l16) * 256 + kb);
#pragma unroll
        for (int nr = 0; nr < 2; ++nr) bfr[nr] = ld_frag(WpT + (size_t)(d0 + nr * 16 + l16) * 256 + kb);
#pragma unroll
        for (int mr = 0; mr < 2; ++mr)
#pragma unroll
            for (int nr = 0; nr < 2; ++nr)
                acc[mr][nr] = MFMA(afr[mr], bfr[nr], acc[mr][nr]);
    }
#pragma unroll
    for (int mr = 0; mr < 2; ++mr)
#pragma unroll
        for (int nr = 0; nr < 2; ++nr) {
            int d = d0 + nr * 16 + l16;
            float bias = bp[d];
#pragma unroll
            for (int r = 0; r < 4; ++r) {
                int i = i0 + mr * 16 + g * 4 + r;
                float v = acc[mr][nr][r] + bias;
                h_f32[(size_t)i * 256 + d] = v;
                hcur_bf[(size_t)i * 256 + d] = f2bf(v);
            }
        }
}

// ---------------- fused message+gate GEMM + kk GEMV + gate L1; writes gmT and gmR ----------------
__global__ __launch_bounds__(256) void k_msgg(const uint16_t* __restrict__ hcur_bf,
                                              const uint16_t* __restrict__ z_bf,
                                              const uint16_t* __restrict__ WmT,
                                              const uint16_t* __restrict__ WgT,
                                              const float* __restrict__ bm,
                                              const float* __restrict__ bg,
                                              const float* __restrict__ wkv,
                                              const float* __restrict__ cvec,
                                              uint16_t* __restrict__ gmT,
                                              uint16_t* __restrict__ gmR,
                                              float* __restrict__ kkv,
                                              float* __restrict__ gsum,
                                              int layer) {
    __shared__ float wkv_s[256];
    __shared__ float wred[4];
    int tid = threadIdx.x;
    wkv_s[tid] = wkv[layer * 256 + tid];
    __syncthreads();

    int bx = blockIdx.x, by = blockIdx.y;
    int lane = tid & 63, wid = tid >> 6;
    int wr = wid >> 1, wc = wid & 1;
    int l16 = lane & 15, g = lane >> 4;
    int i0 = bx * 64 + wr * 32, d0 = by * 64 + wc * 32;
    bool doKK = (by == 0);
    const uint16_t* WmTl = WmT + layer * 65536;
    const uint16_t* WgTl = WgT + layer * 98304;
    f32x4 am[2][2] = {}, ag[2][2] = {};
    float kkp[2] = {0.f, 0.f};
#pragma unroll
    for (int ks = 0; ks < 8; ++ks) {
        int kb = ks * 32 + g * 8;
        bf16x8 afr[2], bmf[2], bgf[2];
#pragma unroll
        for (int mr = 0; mr < 2; ++mr) afr[mr] = ld_frag(hcur_bf + (size_t)(i0 + mr * 16 + l16) * 256 + kb);
#pragma unroll
        for (int nr = 0; nr < 2; ++nr) {
            bmf[nr] = ld_frag(WmTl + (size_t)(d0 + nr * 16 + l16) * 256 + kb);
            bgf[nr] = ld_frag(WgTl + (size_t)(d0 + nr * 16 + l16) * 384 + kb);
        }
        if (doKK) {
#pragma unroll
            for (int mr = 0; mr < 2; ++mr)
#pragma unroll
                for (int u = 0; u < 8; ++u)
                    kkp[mr] += bf2f((uint16_t)afr[mr][u]) * wkv_s[kb + u];
        }
#pragma unroll
        for (int mr = 0; mr < 2; ++mr)
#pragma unroll
            for (int nr = 0; nr < 2; ++nr) {
                am[mr][nr] = MFMA(afr[mr], bmf[nr], am[mr][nr]);
                ag[mr][nr] = MFMA(afr[mr], bgf[nr], ag[mr][nr]);
            }
    }
#pragma unroll
    for (int ks = 0; ks < 4; ++ks) {   // z part of concat: k = 256..383
        int kb = ks * 32 + g * 8;
        bf16x8 afr[2], bgf[2];
#pragma unroll
        for (int mr = 0; mr < 2; ++mr) afr[mr] = ld_frag(z_bf + (size_t)(i0 + mr * 16 + l16) * 128 + kb);
#pragma unroll
        for (int nr = 0; nr < 2; ++nr) bgf[nr] = ld_frag(WgTl + (size_t)(d0 + nr * 16 + l16) * 384 + 256 + kb);
#pragma unroll
        for (int mr = 0; mr < 2; ++mr)
#pragma unroll
            for (int nr = 0; nr < 2; ++nr)
                ag[mr][nr] = MFMA(afr[mr], bgf[nr], ag[mr][nr]);
    }
    float gs = 0.f;
#pragma unroll
    for (int mr = 0; mr < 2; ++mr)
#pragma unroll
        for (int nr = 0; nr < 2; ++nr) {
            int d = d0 + nr * 16 + l16;
            float bmv = bm[layer * 256 + d], bgv = bg[layer * 256 + d];
            ushort4 pack;
#pragma unroll
            for (int r = 0; r < 4; ++r) {
                float rm = am[mr][nr][r] + bmv; rm = rm > 0.f ? rm : 0.f;
                float gt = 1.f / (1.f + __expf(-(ag[mr][nr][r] + bgv)));
                gs += gt;
                float gmv = gt * rm;
                uint16_t gb = f2bf(gmv);
                ((uint16_t*)&pack)[r] = gb;
                gmR[(size_t)(i0 + mr * 16 + g * 4 + r) * 256 + d] = gb;
            }
            int i = i0 + mr * 16 + g * 4;
            *reinterpret_cast<ushort4*>(gmT + (size_t)d * cN + i) = pack;
        }
    // kk: complete within by==0 block; fold constants cq + ck
    if (doKK) {
        float cc = cvec[layer * 2 + 0] + cvec[layer * 2 + 1];
#pragma unroll
        for (int mr = 0; mr < 2; ++mr) {
            float v = kkp[mr];
            v += __shfl_xor(v, 16, 64);
            v += __shfl_xor(v, 32, 64);
            if (lane < 16) kkv[i0 + mr * 16 + l16] = v + cc;
        }
    }
    for (int off = 32; off; off >>= 1) gs += __shfl_down(gs, off, 64);
    if (lane == 0) wred[wid] = gs;
    __syncthreads();
    if (tid == 0) atomicAdd(gsum, wred[0] + wred[1] + wred[2] + wred[3]);
}

// ---------------- per-row: qq = gmR[i,:].wqv ; den = sum_masked exp(lrelu(qq+kk)) ----------------
__global__ __launch_bounds__(256) void k_stats(const uint16_t* __restrict__ gmR,
                                               const float* __restrict__ wqv,
                                               const float* __restrict__ kkv,
                                               const uint32_t* __restrict__ maskw,
                                               float2* __restrict__ stats2, int layer) {
    int wid = threadIdx.x >> 6, lane = threadIdx.x & 63;
    int i = blockIdx.x * 4 + wid;
    ushort4 gv = reinterpret_cast<const ushort4*>(gmR + (size_t)i * 256)[lane];
    float4 wv = reinterpret_cast<const float4*>(wqv + layer * 256)[lane];
    float qq = bf2f(gv.x) * wv.x + bf2f(gv.y) * wv.y + bf2f(gv.z) * wv.z + bf2f(gv.w) * wv.w;
#pragma unroll
    for (int off = 32; off; off >>= 1) qq += __shfl_xor(qq, off, 64);
    const uint32_t* mrow = maskw + (size_t)i * 128;
    float den = 0.f;
#pragma unroll 4
    for (int c = 0; c < 64; ++c) {
        int j = c * 64 + lane;
        uint32_t w = mrow[j >> 5];
        bool on = (w >> (j & 31)) & 1;
        float e = qq + kkv[j];
        e = e > 0.f ? e : 0.01f * e;
        den += on ? __expf(fminf(e, 80.f)) : 0.f;
    }
#pragma unroll
    for (int off = 32; off; off >>= 1) den += __shfl_xor(den, off, 64);
    if (lane == 0) stats2[i] = make_float2(qq, den > 0.f ? 1.f / den : 0.f);
}

// ---------------- agg: full-K flash GEMM + fused residual/recast/output ----------------
// grid (128 j-tiles of 32, 2 d-halves), 256 threads = 4 waves (wave owns 32 d)
__global__ __launch_bounds__(256) void k_agg(const uint16_t* __restrict__ gmT,
                                             const float2* __restrict__ stats2,
                                             const uint32_t* __restrict__ maskw,
                                             const float* __restrict__ kkv,
                                             float* __restrict__ h_f32,
                                             uint16_t* __restrict__ hcur,
                                             float* __restrict__ out, int last) {
    constexpr int ASTR = 136;
    __shared__ uint16_t A_lds[2][32 * ASTR];
    int jt0 = blockIdx.x * 32;
    int by = blockIdx.y;
    int tid = threadIdx.x, lane = tid & 63, wid = tid >> 6;
    int l16 = lane & 15, g = lane >> 4;
    int dbase = by * 128 + wid * 32;
    int jj = tid & 31;
    int io = (tid >> 5) * 16;
    float kkj = kkv[jt0 + jj];
    int wq = jt0 >> 5;
    f32x4 acc[2][2] = {};

    auto wcompute = [&](int s, int b) {
        int ib = s * 128 + io;
        uint16_t* dst = &A_lds[b][jj * ASTR + io];
#pragma unroll
        for (int c = 0; c < 2; ++c) {
            uint16_t wb[8];
#pragma unroll
            for (int u = 0; u < 8; ++u) {
                int i = ib + c * 8 + u;
                float2 st = stats2[i];
                uint32_t wrd = maskw[(size_t)i * 128 + wq];
                float e = st.x + kkj;
                e = e > 0.f ? e : 0.01f * e;
                float w = ((wrd >> jj) & 1) ? __expf(fminf(e, 80.f)) * st.y : 0.f;
                wb[u] = f2bf(w);
            }
            *reinterpret_cast<uint4*>(dst + c * 8) = *reinterpret_cast<uint4*>(wb);
        }
    };

    wcompute(0, 0);
    __syncthreads();
    for (int s = 0; s < 32; ++s) {
        int ibase = s * 128;
        // B prefetch into registers first: exp VALU below covers the L2 latency
        bf16x8 bfr[4][2];
#pragma unroll
        for (int ks = 0; ks < 4; ++ks)
#pragma unroll
            for (int nr = 0; nr < 2; ++nr)
                bfr[ks][nr] = ld_frag(gmT + (size_t)(dbase + nr * 16 + l16) * cN + ibase + ks * 32 + g * 8);
        if (s < 31) wcompute(s + 1, (s + 1) & 1);
        const uint16_t* Ab = A_lds[s & 1];
#pragma unroll
        for (int ks = 0; ks < 4; ++ks) {
            bf16x8 afr[2];
#pragma unroll
            for (int mr = 0; mr < 2; ++mr)
                afr[mr] = ld_frag(&Ab[(mr * 16 + l16) * ASTR + ks * 32 + g * 8]);
#pragma unroll
            for (int mr = 0; mr < 2; ++mr)
#pragma unroll
                for (int nr = 0; nr < 2; ++nr)
                    acc[mr][nr] = MFMA(afr[mr], bfr[ks][nr], acc[mr][nr]);
        }
        __syncthreads();
    }
    // fused residual tail: h = (agg + h)/2, refresh bf16 mirror, emit output on last layer
#pragma unroll
    for (int mr = 0; mr < 2; ++mr)
#pragma unroll
        for (int nr = 0; nr < 2; ++nr) {
            int d = dbase + nr * 16 + l16;
#pragma unroll
            for (int r = 0; r < 4; ++r) {
                int j = jt0 + mr * 16 + g * 4 + r;
                size_t idx = (size_t)j * 256 + d;
                float v = (acc[mr][nr][r] + h_f32[idx]) * 0.5f;
                h_f32[idx] = v;
                hcur[idx] = f2bf(v);
                if (last) out[idx] = v;
            }
        }
}

__global__ void k_fin(const float* __restrict__ gsum, float* __restrict__ out) {
    out[(size_t)cN * cHID] = gsum[0] * (1.f / ((float)(cN * cHID) * (float)cL));
}

// ---------------- host side ----------------
extern "C" void kernel_launch(void* const* d_in, const int* in_sizes, int n_in,
                              void* d_out, int out_size, void* d_ws, size_t ws_size,
                              hipStream_t stream) {
    const float* h   = (const float*)d_in[0];
    const int*   adj = (const int*)d_in[1];
    const float* z   = (const float*)d_in[2];
    const float* Wp  = (const float*)d_in[3];
    const float* bp  = (const float*)d_in[4];
    const float* Wm  = (const float*)d_in[5];
    const float* bm  = (const float*)d_in[6];
    const float* Wg  = (const float*)d_in[7];
    const float* bg  = (const float*)d_in[8];
    const float* Wk  = (const float*)d_in[9];
    const float* bk  = (const float*)d_in[10];
    const float* Wq  = (const float*)d_in[11];
    const float* bq  = (const float*)d_in[12];
    const float* a   = (const float*)d_in[13];
    float* out = (float*)d_out;

    uint8_t* ws = (uint8_t*)d_ws;
    size_t cur = 0;
    auto alloc = [&](size_t bytes) -> uint8_t* {
        uint8_t* p = ws + cur;
        cur = (cur + bytes + 255) & ~(size_t)255;
        return p;
    };
    uint32_t* maskw  = (uint32_t*)alloc((size_t)cN * 128 * 4);
    float*    h_f32  = (float*)   alloc((size_t)cN * 256 * 4);
    uint16_t* hin_bf = (uint16_t*)alloc((size_t)cN * 256 * 2);
    uint16_t* hcur   = (uint16_t*)alloc((size_t)cN * 256 * 2);
    uint16_t* z_bf   = (uint16_t*)alloc((size_t)cN * 128 * 2);
    uint16_t* WpT    = (uint16_t*)alloc(65536 * 2);
    uint16_t* WmT    = (uint16_t*)alloc((size_t)cL * 65536 * 2);
    uint16_t* WgT    = (uint16_t*)alloc((size_t)cL * 98304 * 2);
    uint16_t* gmT    = (uint16_t*)alloc((size_t)cN * 256 * 2);
    uint16_t* gmR    = (uint16_t*)alloc((size_t)cN * 256 * 2);
    float*    wqv    = (float*)   alloc(cL * 256 * 4);
    float*    wkv    = (float*)   alloc(cL * 256 * 4);
    float*    cvec   = (float*)   alloc(256);
    float*    kk     = (float*)   alloc(cN * 4);
    float2*   stats2 = (float2*)  alloc(cN * 8);
    float*    gsum   = (float*)   alloc(256);
    (void)cur;

    hipMemsetAsync(gsum, 0, 4, stream);

    // 1024 (h) + 512 (z) + 16 (Wp) + 32 (Wm) + 48 (Wg) + 16 (wvec) = 1648 blocks
    k_prep<<<1648, 256, 0, stream>>>(h, z, Wp, Wm, Wg, Wq, bq, Wk, bk, a,
                                     hin_bf, z_bf, WpT, WmT, WgT, wqv, wkv, cvec);
    k_bits<<<cN / 4, 256, 0, stream>>>(adj, maskw);
    k_proj<<<dim3(64, 4), 256, 0, stream>>>(hin_bf, WpT, bp, h_f32, hcur);

    for (int l = 0; l < cL; ++l) {
        k_msgg<<<dim3(64, 4), 256, 0, stream>>>(hcur, z_bf, WmT, WgT, bm, bg,
                                                wkv, cvec, gmT, gmR, kk, gsum, l);
        k_stats<<<cN / 4, 256, 0, stream>>>(gmR, wqv, kk, maskw, stats2, l);
        k_agg<<<dim3(cN / 32, 2), 256, 0, stream>>>(gmT, stats2, maskw, kk,
                                                    h_f32, hcur, out, l == cL - 1 ? 1 : 0);
    }
    k_fin<<<1, 1, 0, stream>>>(gsum, out);
}

// Round 4
// 235.502 us; speedup vs baseline: 2.4649x; 2.4649x over previous
//
#include <hip/hip_runtime.h>
#include <hip/hip_bf16.h>
#include <stdint.h>

static constexpr int cN    = 4096;
static constexpr int cHID  = 256;
static constexpr int cTASK = 128;
static constexpr int cL    = 2;

typedef short bf16x8 __attribute__((ext_vector_type(8)));
typedef float f32x4  __attribute__((ext_vector_type(4)));

#define MFMA(a, b, c) __builtin_amdgcn_mfma_f32_16x16x32_bf16((a), (b), (c), 0, 0, 0)

static __device__ __forceinline__ uint16_t f2bf(float f) {
    uint32_t u = __float_as_uint(f);
    uint32_t r = (u + 0x7FFFu + ((u >> 16) & 1u)) >> 16;
    return (uint16_t)r;
}
static __device__ __forceinline__ float bf2f(uint16_t h) {
    return __uint_as_float(((uint32_t)h) << 16);
}
static __device__ __forceinline__ bf16x8 ld_frag(const uint16_t* p) {
    return *reinterpret_cast<const bf16x8*>(p);
}
// spread byte bits t -> bit 4t
static __device__ __forceinline__ uint32_t spread4(uint32_t x) {
    x = (x | (x << 12)) & 0x000F000Fu;
    x = (x | (x << 6))  & 0x03030303u;
    x = (x | (x << 3))  & 0x11111111u;
    return x;
}

// ---------------- merged prep: casts + weight transposes + attention-vector fold ----------------
static __device__ __forceinline__ void castT_body(const float* __restrict__ S,
                                                  uint16_t* __restrict__ D, int K, int bx,
                                                  uint16_t (*t)[72]) {
    int ntk = K / 64;
    int tk = (bx % ntk) * 64;
    int td = (bx / ntk) * 64;
    int lane = threadIdx.x & 63, w = threadIdx.x >> 6;
    for (int r = w; r < 64; r += 4) t[r][lane] = f2bf(S[(size_t)(tk + r) * 256 + td + lane]);
    __syncthreads();
    for (int r = w; r < 64; r += 4) D[(size_t)(td + r) * K + tk + lane] = t[lane][r];
}

__global__ __launch_bounds__(256) void k_prep(const float* __restrict__ h,
                                              const float* __restrict__ z,
                                              const float* __restrict__ Wp,
                                              const float* __restrict__ Wm,
                                              const float* __restrict__ Wg,
                                              const float* __restrict__ Wq,
                                              const float* __restrict__ bq,
                                              const float* __restrict__ Wk,
                                              const float* __restrict__ bk,
                                              const float* __restrict__ a,
                                              uint16_t* __restrict__ hin_bf,
                                              uint16_t* __restrict__ z_bf,
                                              uint16_t* __restrict__ WpT,
                                              uint16_t* __restrict__ WmT,
                                              uint16_t* __restrict__ WgT,
                                              float* __restrict__ wqv,
                                              float* __restrict__ wkv,
                                              float* __restrict__ cvec) {
    __shared__ uint16_t sht[64][72];
    __shared__ float shf[2][256];
    int b = blockIdx.x, tid = threadIdx.x;
    if (b < 1024) {                                    // h cast (vec4)
        int idx = b * 256 + tid;
        float4 v = reinterpret_cast<const float4*>(h)[idx];
        ushort4 o; o.x = f2bf(v.x); o.y = f2bf(v.y); o.z = f2bf(v.z); o.w = f2bf(v.w);
        reinterpret_cast<ushort4*>(hin_bf)[idx] = o;
        return;
    }
    b -= 1024;
    if (b < 512) {                                     // z cast (vec4)
        int idx = b * 256 + tid;
        float4 v = reinterpret_cast<const float4*>(z)[idx];
        ushort4 o; o.x = f2bf(v.x); o.y = f2bf(v.y); o.z = f2bf(v.z); o.w = f2bf(v.w);
        reinterpret_cast<ushort4*>(z_bf)[idx] = o;
        return;
    }
    b -= 512;
    if (b < 16) { castT_body(Wp, WpT, 256, b, sht); return; }
    b -= 16;
    if (b < 32) { castT_body(Wm + (b >> 4) * 65536, WmT + (b >> 4) * 65536, 256, b & 15, sht); return; }
    b -= 32;
    if (b < 48) { castT_body(Wg + (b / 24) * 98304, WgT + (b / 24) * 98304, 384, b % 24, sht); return; }
    b -= 48;
    {   // wvec: 16 blocks: l = b>>3, which = (b>>2)&1, q = b&3
        int l = b >> 3, which = (b >> 2) & 1, q = b & 3;
        int lane = tid & 63, wid = tid >> 6;
        const float* W    = which ? (Wk + l * 65536) : (Wq + l * 65536);
        const float* avec = a + l * 512 + (which ? 0 : 256);
        float* av = shf[0];
        float* red = shf[1];
        av[tid] = avec[tid];
        __syncthreads();
        float av0 = av[lane], av1 = av[64 + lane], av2 = av[128 + lane], av3 = av[192 + lane];
        float* wv = which ? wkv : wqv;
        for (int dd = 0; dd < 16; ++dd) {
            int d = q * 64 + wid * 16 + dd;
            const float* Wr = W + (size_t)d * 256;
            float s = Wr[lane] * av0 + Wr[64 + lane] * av1 + Wr[128 + lane] * av2 + Wr[192 + lane] * av3;
            for (int off = 32; off; off >>= 1) s += __shfl_down(s, off, 64);
            if (lane == 0) wv[l * 256 + d] = s;
        }
        if (q == 0) {
            const float* bias = which ? (bk + l * 256) : (bq + l * 256);
            red[tid] = bias[tid] * av[tid];
            __syncthreads();
            for (int off = 128; off; off >>= 1) {
                if (tid < off) red[tid] += red[tid + off];
                __syncthreads();
            }
            if (tid == 0) cvec[l * 2 + which] = red[0];
        }
    }
}

// ---------------- adj -> bitmask, int4 loads + ballot pack ----------------
__global__ __launch_bounds__(256) void k_bits(const int* __restrict__ adj,
                                              uint32_t* __restrict__ maskw) {
    int wid = threadIdx.x >> 6, lane = threadIdx.x & 63;
    int i = blockIdx.x * 4 + wid;
    const int* row = adj + (size_t)i * cN;
    uint32_t* orow = maskw + (size_t)i * 128;
    for (int ch = 0; ch < 16; ++ch) {
        int4 v = reinterpret_cast<const int4*>(row + ch * 256)[lane];
        uint64_t b0 = __ballot(v.x > 0);
        uint64_t b1 = __ballot(v.y > 0);
        uint64_t b2 = __ballot(v.z > 0);
        uint64_t b3 = __ballot(v.w > 0);
        int k = lane & 7;
        uint32_t e0 = spread4((uint32_t)(b0 >> (8 * k)) & 0xFFu);
        uint32_t e1 = spread4((uint32_t)(b1 >> (8 * k)) & 0xFFu);
        uint32_t e2 = spread4((uint32_t)(b2 >> (8 * k)) & 0xFFu);
        uint32_t e3 = spread4((uint32_t)(b3 >> (8 * k)) & 0xFFu);
        if (lane < 8) orow[ch * 8 + k] = e0 | (e1 << 1) | (e2 << 2) | (e3 << 3);
    }
}

// ---------------- initial projection: h = hin @ Wp + bp ----------------
__global__ __launch_bounds__(256) void k_proj(const uint16_t* __restrict__ hin_bf,
                                              const uint16_t* __restrict__ WpT,
                                              const float* __restrict__ bp,
                                              float* __restrict__ h_f32,
                                              uint16_t* __restrict__ hcur_bf) {
    int bx = blockIdx.x, by = blockIdx.y;
    int tid = threadIdx.x, lane = tid & 63, wid = tid >> 6;
    int wr = wid >> 1, wc = wid & 1;
    int l16 = lane & 15, g = lane >> 4;
    int i0 = bx * 64 + wr * 32, d0 = by * 64 + wc * 32;
    f32x4 acc[2][2] = {};
#pragma unroll
    for (int ks = 0; ks < 8; ++ks) {
        int kb = ks * 32 + g * 8;
        bf16x8 afr[2], bfr[2];
#pragma unroll
        for (int mr = 0; mr < 2; ++mr) afr[mr] = ld_frag(hin_bf + (size_t)(i0 + mr * 16 + l16) * 256 + kb);
#pragma unroll
        for (int nr = 0; nr < 2; ++nr) bfr[nr] = ld_frag(WpT + (size_t)(d0 + nr * 16 + l16) * 256 + kb);
#pragma unroll
        for (int mr = 0; mr < 2; ++mr)
#pragma unroll
            for (int nr = 0; nr < 2; ++nr)
                acc[mr][nr] = MFMA(afr[mr], bfr[nr], acc[mr][nr]);
    }
#pragma unroll
    for (int mr = 0; mr < 2; ++mr)
#pragma unroll
        for (int nr = 0; nr < 2; ++nr) {
            int d = d0 + nr * 16 + l16;
            float bias = bp[d];
#pragma unroll
            for (int r = 0; r < 4; ++r) {
                int i = i0 + mr * 16 + g * 4 + r;
                float v = acc[mr][nr][r] + bias;
                h_f32[(size_t)i * 256 + d] = v;
                hcur_bf[(size_t)i * 256 + d] = f2bf(v);
            }
        }
}

// ---------------- fused message+gate GEMM + kk GEMV + gate L1; writes gmT and gmR ----------------
__global__ __launch_bounds__(256) void k_msgg(const uint16_t* __restrict__ hcur_bf,
                                              const uint16_t* __restrict__ z_bf,
                                              const uint16_t* __restrict__ WmT,
                                              const uint16_t* __restrict__ WgT,
                                              const float* __restrict__ bm,
                                              const float* __restrict__ bg,
                                              const float* __restrict__ wkv,
                                              const float* __restrict__ cvec,
                                              uint16_t* __restrict__ gmT,
                                              uint16_t* __restrict__ gmR,
                                              float* __restrict__ kkv,
                                              float* __restrict__ gsum,
                                              int layer) {
    __shared__ float wkv_s[256];
    __shared__ float wred[4];
    int tid = threadIdx.x;
    wkv_s[tid] = wkv[layer * 256 + tid];
    __syncthreads();

    int bx = blockIdx.x, by = blockIdx.y;
    int lane = tid & 63, wid = tid >> 6;
    int wr = wid >> 1, wc = wid & 1;
    int l16 = lane & 15, g = lane >> 4;
    int i0 = bx * 64 + wr * 32, d0 = by * 64 + wc * 32;
    bool doKK = (by == 0);
    const uint16_t* WmTl = WmT + layer * 65536;
    const uint16_t* WgTl = WgT + layer * 98304;
    f32x4 am[2][2] = {}, ag[2][2] = {};
    float kkp[2] = {0.f, 0.f};
#pragma unroll
    for (int ks = 0; ks < 8; ++ks) {
        int kb = ks * 32 + g * 8;
        bf16x8 afr[2], bmf[2], bgf[2];
#pragma unroll
        for (int mr = 0; mr < 2; ++mr) afr[mr] = ld_frag(hcur_bf + (size_t)(i0 + mr * 16 + l16) * 256 + kb);
#pragma unroll
        for (int nr = 0; nr < 2; ++nr) {
            bmf[nr] = ld_frag(WmTl + (size_t)(d0 + nr * 16 + l16) * 256 + kb);
            bgf[nr] = ld_frag(WgTl + (size_t)(d0 + nr * 16 + l16) * 384 + kb);
        }
        if (doKK) {
#pragma unroll
            for (int mr = 0; mr < 2; ++mr)
#pragma unroll
                for (int u = 0; u < 8; ++u)
                    kkp[mr] += bf2f((uint16_t)afr[mr][u]) * wkv_s[kb + u];
        }
#pragma unroll
        for (int mr = 0; mr < 2; ++mr)
#pragma unroll
            for (int nr = 0; nr < 2; ++nr) {
                am[mr][nr] = MFMA(afr[mr], bmf[nr], am[mr][nr]);
                ag[mr][nr] = MFMA(afr[mr], bgf[nr], ag[mr][nr]);
            }
    }
#pragma unroll
    for (int ks = 0; ks < 4; ++ks) {   // z part of concat: k = 256..383
        int kb = ks * 32 + g * 8;
        bf16x8 afr[2], bgf[2];
#pragma unroll
        for (int mr = 0; mr < 2; ++mr) afr[mr] = ld_frag(z_bf + (size_t)(i0 + mr * 16 + l16) * 128 + kb);
#pragma unroll
        for (int nr = 0; nr < 2; ++nr) bgf[nr] = ld_frag(WgTl + (size_t)(d0 + nr * 16 + l16) * 384 + 256 + kb);
#pragma unroll
        for (int mr = 0; mr < 2; ++mr)
#pragma unroll
            for (int nr = 0; nr < 2; ++nr)
                ag[mr][nr] = MFMA(afr[mr], bgf[nr], ag[mr][nr]);
    }
    float gs = 0.f;
#pragma unroll
    for (int mr = 0; mr < 2; ++mr)
#pragma unroll
        for (int nr = 0; nr < 2; ++nr) {
            int d = d0 + nr * 16 + l16;
            float bmv = bm[layer * 256 + d], bgv = bg[layer * 256 + d];
            ushort4 pack;
#pragma unroll
            for (int r = 0; r < 4; ++r) {
                float rm = am[mr][nr][r] + bmv; rm = rm > 0.f ? rm : 0.f;
                float gt = 1.f / (1.f + __expf(-(ag[mr][nr][r] + bgv)));
                gs += gt;
                float gmv = gt * rm;
                uint16_t gb = f2bf(gmv);
                ((uint16_t*)&pack)[r] = gb;
                gmR[(size_t)(i0 + mr * 16 + g * 4 + r) * 256 + d] = gb;
            }
            int i = i0 + mr * 16 + g * 4;
            *reinterpret_cast<ushort4*>(gmT + (size_t)d * cN + i) = pack;
        }
    // kk: complete within by==0 block; fold constants cq + ck
    if (doKK) {
        float cc = cvec[layer * 2 + 0] + cvec[layer * 2 + 1];
#pragma unroll
        for (int mr = 0; mr < 2; ++mr) {
            float v = kkp[mr];
            v += __shfl_xor(v, 16, 64);
            v += __shfl_xor(v, 32, 64);
            if (lane < 16) kkv[i0 + mr * 16 + l16] = v + cc;
        }
    }
    for (int off = 32; off; off >>= 1) gs += __shfl_down(gs, off, 64);
    if (lane == 0) wred[wid] = gs;
    __syncthreads();
    if (tid == 0) atomicAdd(gsum, wred[0] + wred[1] + wred[2] + wred[3]);
}

// ---------------- per-row: qq = gmR[i,:].wqv ; den = sum_masked exp(lrelu(qq+kk)) ----------------
__global__ __launch_bounds__(256) void k_stats(const uint16_t* __restrict__ gmR,
                                               const float* __restrict__ wqv,
                                               const float* __restrict__ kkv,
                                               const uint32_t* __restrict__ maskw,
                                               float2* __restrict__ stats2, int layer) {
    int wid = threadIdx.x >> 6, lane = threadIdx.x & 63;
    int i = blockIdx.x * 4 + wid;
    ushort4 gv = reinterpret_cast<const ushort4*>(gmR + (size_t)i * 256)[lane];
    float4 wv = reinterpret_cast<const float4*>(wqv + layer * 256)[lane];
    float qq = bf2f(gv.x) * wv.x + bf2f(gv.y) * wv.y + bf2f(gv.z) * wv.z + bf2f(gv.w) * wv.w;
#pragma unroll
    for (int off = 32; off; off >>= 1) qq += __shfl_xor(qq, off, 64);
    const uint32_t* mrow = maskw + (size_t)i * 128;
    float den = 0.f;
#pragma unroll 4
    for (int c = 0; c < 64; ++c) {
        int j = c * 64 + lane;
        uint32_t w = mrow[j >> 5];
        bool on = (w >> (j & 31)) & 1;
        float e = qq + kkv[j];
        e = e > 0.f ? e : 0.01f * e;
        den += on ? __expf(fminf(e, 80.f)) : 0.f;
    }
#pragma unroll
    for (int off = 32; off; off >>= 1) den += __shfl_xor(den, off, 64);
    if (lane == 0) stats2[i] = make_float2(qq, den > 0.f ? 1.f / den : 0.f);
}

// ---------------- agg: attention^T @ gm, K-split, 8 waves cover all 256 d ----------------
// grid (128 j-tiles of 32, 4 K-segs of 1024), 512 threads. One barrier/stage, dbuf A in LDS.
__global__ __launch_bounds__(512, 4) void k_agg(const uint16_t* __restrict__ gmT,
                                                const float2* __restrict__ stats2,
                                                const uint32_t* __restrict__ maskw,
                                                const float* __restrict__ kkv,
                                                float* __restrict__ part) {
    constexpr int ASTR = 40;                    // 80B row stride: 16B-aligned frags, low conflict
    __shared__ uint16_t A_lds[2][32 * ASTR];
    int jt0 = blockIdx.x * 32;
    int seg = blockIdx.y;
    int tid = threadIdx.x, lane = tid & 63, wid = tid >> 6;   // 8 waves, wave owns 32 d
    int l16 = lane & 15, g = lane >> 4;
    int d0 = wid * 32;
    int jj = tid & 31;
    int iog = tid >> 5;                         // 0..15, 2 i's per thread
    float kkj = kkv[jt0 + jj];
    int wq = jt0 >> 5;
    int ib0 = seg * 1024;
    f32x4 acc[2][2] = {};

    auto wcompute = [&](int s, int b) {
        int i = ib0 + s * 32 + iog * 2;
        float2 st0 = stats2[i];
        float2 st1 = stats2[i + 1];
        uint32_t w0 = maskw[(size_t)i * 128 + wq];
        uint32_t w1 = maskw[(size_t)(i + 1) * 128 + wq];
        float e0 = st0.x + kkj; e0 = e0 > 0.f ? e0 : 0.01f * e0;
        float e1 = st1.x + kkj; e1 = e1 > 0.f ? e1 : 0.01f * e1;
        float v0 = ((w0 >> jj) & 1) ? __expf(fminf(e0, 80.f)) * st0.y : 0.f;
        float v1 = ((w1 >> jj) & 1) ? __expf(fminf(e1, 80.f)) * st1.y : 0.f;
        uint32_t pk = (uint32_t)f2bf(v0) | ((uint32_t)f2bf(v1) << 16);
        *reinterpret_cast<uint32_t*>(&A_lds[b][jj * ASTR + iog * 2]) = pk;
    };

    wcompute(0, 0);
    __syncthreads();
    for (int s = 0; s < 32; ++s) {
        // B prefetch into registers first; wcompute VALU below covers L2 latency
        int ic = ib0 + s * 32 + g * 8;
        bf16x8 bfr0 = ld_frag(gmT + (size_t)(d0 + l16) * cN + ic);
        bf16x8 bfr1 = ld_frag(gmT + (size_t)(d0 + 16 + l16) * cN + ic);
        if (s < 31) wcompute(s + 1, (s + 1) & 1);
        const uint16_t* Ab = A_lds[s & 1];
        bf16x8 a0 = ld_frag(&Ab[l16 * ASTR + g * 8]);
        bf16x8 a1 = ld_frag(&Ab[(16 + l16) * ASTR + g * 8]);
        acc[0][0] = MFMA(a0, bfr0, acc[0][0]);
        acc[0][1] = MFMA(a0, bfr1, acc[0][1]);
        acc[1][0] = MFMA(a1, bfr0, acc[1][0]);
        acc[1][1] = MFMA(a1, bfr1, acc[1][1]);
        __syncthreads();
    }
#pragma unroll
    for (int mr = 0; mr < 2; ++mr)
#pragma unroll
        for (int nr = 0; nr < 2; ++nr) {
            int d = d0 + nr * 16 + l16;
#pragma unroll
            for (int r = 0; r < 4; ++r) {
                int j = jt0 + mr * 16 + g * 4 + r;
                part[((size_t)seg * cN + j) * 256 + d] = acc[mr][nr][r];
            }
        }
}

// ---------------- residual: h = (sum(parts) + h)/2; refresh bf16 mirror; maybe emit output ----------------
__global__ __launch_bounds__(256) void k_resid(const float* __restrict__ part,
                                               float* __restrict__ h_f32,
                                               uint16_t* __restrict__ hcur_bf,
                                               float* __restrict__ out,
                                               int last) {
    int idx = blockIdx.x * 256 + threadIdx.x;
    float4 acc = reinterpret_cast<float4*>(h_f32)[idx];
#pragma unroll
    for (int p = 0; p < 4; ++p) {
        float4 v = reinterpret_cast<const float4*>(part + (size_t)p * cN * 256)[idx];
        acc.x += v.x; acc.y += v.y; acc.z += v.z; acc.w += v.w;
    }
    acc.x *= 0.5f; acc.y *= 0.5f; acc.z *= 0.5f; acc.w *= 0.5f;
    reinterpret_cast<float4*>(h_f32)[idx] = acc;
    ushort4 hb; hb.x = f2bf(acc.x); hb.y = f2bf(acc.y); hb.z = f2bf(acc.z); hb.w = f2bf(acc.w);
    reinterpret_cast<ushort4*>(hcur_bf)[idx] = hb;
    if (last) reinterpret_cast<float4*>(out)[idx] = acc;
}

__global__ void k_fin(const float* __restrict__ gsum, float* __restrict__ out) {
    out[(size_t)cN * cHID] = gsum[0] * (1.f / ((float)(cN * cHID) * (float)cL));
}

// ---------------- host side ----------------
extern "C" void kernel_launch(void* const* d_in, const int* in_sizes, int n_in,
                              void* d_out, int out_size, void* d_ws, size_t ws_size,
                              hipStream_t stream) {
    const float* h   = (const float*)d_in[0];
    const int*   adj = (const int*)d_in[1];
    const float* z   = (const float*)d_in[2];
    const float* Wp  = (const float*)d_in[3];
    const float* bp  = (const float*)d_in[4];
    const float* Wm  = (const float*)d_in[5];
    const float* bm  = (const float*)d_in[6];
    const float* Wg  = (const float*)d_in[7];
    const float* bg  = (const float*)d_in[8];
    const float* Wk  = (const float*)d_in[9];
    const float* bk  = (const float*)d_in[10];
    const float* Wq  = (const float*)d_in[11];
    const float* bq  = (const float*)d_in[12];
    const float* a   = (const float*)d_in[13];
    float* out = (float*)d_out;

    uint8_t* ws = (uint8_t*)d_ws;
    size_t cur = 0;
    auto alloc = [&](size_t bytes) -> uint8_t* {
        uint8_t* p = ws + cur;
        cur = (cur + bytes + 255) & ~(size_t)255;
        return p;
    };
    uint32_t* maskw  = (uint32_t*)alloc((size_t)cN * 128 * 4);
    float*    h_f32  = (float*)   alloc((size_t)cN * 256 * 4);
    uint16_t* hin_bf = (uint16_t*)alloc((size_t)cN * 256 * 2);
    uint16_t* hcur   = (uint16_t*)alloc((size_t)cN * 256 * 2);
    uint16_t* z_bf   = (uint16_t*)alloc((size_t)cN * 128 * 2);
    uint16_t* WpT    = (uint16_t*)alloc(65536 * 2);
    uint16_t* WmT    = (uint16_t*)alloc((size_t)cL * 65536 * 2);
    uint16_t* WgT    = (uint16_t*)alloc((size_t)cL * 98304 * 2);
    uint16_t* gmT    = (uint16_t*)alloc((size_t)cN * 256 * 2);
    uint16_t* gmR    = (uint16_t*)alloc((size_t)cN * 256 * 2);
    float*    wqv    = (float*)   alloc(cL * 256 * 4);
    float*    wkv    = (float*)   alloc(cL * 256 * 4);
    float*    cvec   = (float*)   alloc(256);
    float*    kk     = (float*)   alloc(cN * 4);
    float2*   stats2 = (float2*)  alloc(cN * 8);
    float*    gsum   = (float*)   alloc(256);
    float*    part   = (float*)   alloc(4ull * cN * 256 * 4);
    (void)cur;

    hipMemsetAsync(gsum, 0, 4, stream);

    // 1024 (h) + 512 (z) + 16 (Wp) + 32 (Wm) + 48 (Wg) + 16 (wvec) = 1648 blocks
    k_prep<<<1648, 256, 0, stream>>>(h, z, Wp, Wm, Wg, Wq, bq, Wk, bk, a,
                                     hin_bf, z_bf, WpT, WmT, WgT, wqv, wkv, cvec);
    k_bits<<<cN / 4, 256, 0, stream>>>(adj, maskw);
    k_proj<<<dim3(64, 4), 256, 0, stream>>>(hin_bf, WpT, bp, h_f32, hcur);

    for (int l = 0; l < cL; ++l) {
        k_msgg<<<dim3(64, 4), 256, 0, stream>>>(hcur, z_bf, WmT, WgT, bm, bg,
                                                wkv, cvec, gmT, gmR, kk, gsum, l);
        k_stats<<<cN / 4, 256, 0, stream>>>(gmR, wqv, kk, maskw, stats2, l);
        k_agg<<<dim3(cN / 32, 4), 512, 0, stream>>>(gmT, stats2, maskw, kk, part);
        k_resid<<<cN * 256 / 4 / 256, 256, 0, stream>>>(part, h_f32, hcur, out, l == cL - 1 ? 1 : 0);
    }
    k_fin<<<1, 1, 0, stream>>>(gsum, out);
}

// Round 6
// 168.802 us; speedup vs baseline: 3.4389x; 1.3951x over previous
//
#include <hip/hip_runtime.h>
#include <hip/hip_bf16.h>
#include <stdint.h>

static constexpr int cN    = 4096;
static constexpr int cHID  = 256;
static constexpr int cTASK = 128;
static constexpr int cL    = 2;
static constexpr float RLN2 = 1.4426950408889634f;   // 1/ln2

typedef short bf16x8 __attribute__((ext_vector_type(8)));
typedef float f32x4  __attribute__((ext_vector_type(4)));

#define MFMA(a, b, c) __builtin_amdgcn_mfma_f32_16x16x32_bf16((a), (b), (c), 0, 0, 0)

static __device__ __forceinline__ uint16_t f2bf(float f) {
    uint32_t u = __float_as_uint(f);
    uint32_t r = (u + 0x7FFFu + ((u >> 16) & 1u)) >> 16;
    return (uint16_t)r;
}
static __device__ __forceinline__ float bf2f(uint16_t h) {
    return __uint_as_float(((uint32_t)h) << 16);
}
static __device__ __forceinline__ bf16x8 ld_frag(const uint16_t* p) {
    return *reinterpret_cast<const bf16x8*>(p);
}
static __device__ __forceinline__ uint32_t spread4(uint32_t x) {
    x = (x | (x << 12)) & 0x000F000Fu;
    x = (x | (x << 6))  & 0x03030303u;
    x = (x | (x << 3))  & 0x11111111u;
    return x;
}

// ---------------- merged prep: casts + weight transposes + attention-vector fold ----------------
static __device__ __forceinline__ void castT_body(const float* __restrict__ S,
                                                  uint16_t* __restrict__ D, int K, int bx,
                                                  uint16_t (*t)[72]) {
    int ntk = K / 64;
    int tk = (bx % ntk) * 64;
    int td = (bx / ntk) * 64;
    int lane = threadIdx.x & 63, w = threadIdx.x >> 6;
    for (int r = w; r < 64; r += 4) t[r][lane] = f2bf(S[(size_t)(tk + r) * 256 + td + lane]);
    __syncthreads();
    for (int r = w; r < 64; r += 4) D[(size_t)(td + r) * K + tk + lane] = t[lane][r];
}

__global__ __launch_bounds__(256) void k_prep(const float* __restrict__ h,
                                              const float* __restrict__ z,
                                              const float* __restrict__ Wp,
                                              const float* __restrict__ Wm,
                                              const float* __restrict__ Wg,
                                              const float* __restrict__ Wq,
                                              const float* __restrict__ bq,
                                              const float* __restrict__ Wk,
                                              const float* __restrict__ bk,
                                              const float* __restrict__ a,
                                              uint16_t* __restrict__ hin_bf,
                                              uint16_t* __restrict__ z_bf,
                                              uint16_t* __restrict__ WpT,
                                              uint16_t* __restrict__ WmT,
                                              uint16_t* __restrict__ WgT,
                                              float* __restrict__ wqv,
                                              float* __restrict__ wkv,
                                              float* __restrict__ cvec) {
    __shared__ uint16_t sht[64][72];
    __shared__ float shf[2][256];
    int b = blockIdx.x, tid = threadIdx.x;
    if (b < 1024) {                                    // h cast (vec4)
        int idx = b * 256 + tid;
        float4 v = reinterpret_cast<const float4*>(h)[idx];
        ushort4 o; o.x = f2bf(v.x); o.y = f2bf(v.y); o.z = f2bf(v.z); o.w = f2bf(v.w);
        reinterpret_cast<ushort4*>(hin_bf)[idx] = o;
        return;
    }
    b -= 1024;
    if (b < 512) {                                     // z cast (vec4)
        int idx = b * 256 + tid;
        float4 v = reinterpret_cast<const float4*>(z)[idx];
        ushort4 o; o.x = f2bf(v.x); o.y = f2bf(v.y); o.z = f2bf(v.z); o.w = f2bf(v.w);
        reinterpret_cast<ushort4*>(z_bf)[idx] = o;
        return;
    }
    b -= 512;
    if (b < 16) { castT_body(Wp, WpT, 256, b, sht); return; }
    b -= 16;
    if (b < 32) { castT_body(Wm + (b >> 4) * 65536, WmT + (b >> 4) * 65536, 256, b & 15, sht); return; }
    b -= 32;
    if (b < 48) { castT_body(Wg + (b / 24) * 98304, WgT + (b / 24) * 98304, 384, b % 24, sht); return; }
    b -= 48;
    {   // wvec: l = b>>3, which = (b>>2)&1, q = b&3  (results scaled by 1/ln2)
        int l = b >> 3, which = (b >> 2) & 1, q = b & 3;
        int lane = tid & 63, wid = tid >> 6;
        const float* W    = which ? (Wk + l * 65536) : (Wq + l * 65536);
        const float* avec = a + l * 512 + (which ? 0 : 256);
        float* av = shf[0];
        float* red = shf[1];
        av[tid] = avec[tid];
        __syncthreads();
        float av0 = av[lane], av1 = av[64 + lane], av2 = av[128 + lane], av3 = av[192 + lane];
        float* wv = which ? wkv : wqv;
        for (int dd = 0; dd < 16; ++dd) {
            int d = q * 64 + wid * 16 + dd;
            const float* Wr = W + (size_t)d * 256;
            float s = Wr[lane] * av0 + Wr[64 + lane] * av1 + Wr[128 + lane] * av2 + Wr[192 + lane] * av3;
            for (int off = 32; off; off >>= 1) s += __shfl_down(s, off, 64);
            if (lane == 0) wv[l * 256 + d] = s * RLN2;
        }
        if (q == 0) {
            const float* bias = which ? (bk + l * 256) : (bq + l * 256);
            red[tid] = bias[tid] * av[tid];
            __syncthreads();
            for (int off = 128; off; off >>= 1) {
                if (tid < off) red[tid] += red[tid + off];
                __syncthreads();
            }
            if (tid == 0) cvec[l * 2 + which] = red[0] * RLN2;
        }
    }
}

// ---------------- adj -> row-major bitmask maskw[i][j/32] ----------------
__global__ __launch_bounds__(256) void k_bits(const int* __restrict__ adj,
                                              uint32_t* __restrict__ maskw) {
    int wid = threadIdx.x >> 6, lane = threadIdx.x & 63;
    int i = blockIdx.x * 4 + wid;
    const int* row = adj + (size_t)i * cN;
    uint32_t* orow = maskw + (size_t)i * 128;
    for (int ch = 0; ch < 16; ++ch) {
        int4 v = reinterpret_cast<const int4*>(row + ch * 256)[lane];
        uint64_t b0 = __ballot(v.x > 0);
        uint64_t b1 = __ballot(v.y > 0);
        uint64_t b2 = __ballot(v.z > 0);
        uint64_t b3 = __ballot(v.w > 0);
        int k = lane & 7;
        uint32_t e0 = spread4((uint32_t)(b0 >> (8 * k)) & 0xFFu);
        uint32_t e1 = spread4((uint32_t)(b1 >> (8 * k)) & 0xFFu);
        uint32_t e2 = spread4((uint32_t)(b2 >> (8 * k)) & 0xFFu);
        uint32_t e3 = spread4((uint32_t)(b3 >> (8 * k)) & 0xFFu);
        if (lane < 8) orow[ch * 8 + k] = e0 | (e1 << 1) | (e2 << 2) | (e3 << 3);
    }
}

// ---------------- bit-transpose: maskT[j][i/32] bit (i&31) = maskw[i][j/32] bit (j&31) ----------------
__global__ __launch_bounds__(256) void k_bitsT(const uint32_t* __restrict__ maskw,
                                               uint32_t* __restrict__ maskT) {
    __shared__ uint32_t ml[256][9];
    int bi = blockIdx.x & 15, bj = blockIdx.x >> 4;
    int i0 = bi * 256, j0 = bj * 256;
    int tid = threadIdx.x;
    {
        const uint32_t* src = maskw + (size_t)(i0 + tid) * 128 + bj * 8;
        uint4 a = *reinterpret_cast<const uint4*>(src);
        uint4 b = *reinterpret_cast<const uint4*>(src + 4);
        ml[tid][0] = a.x; ml[tid][1] = a.y; ml[tid][2] = a.z; ml[tid][3] = a.w;
        ml[tid][4] = b.x; ml[tid][5] = b.y; ml[tid][6] = b.z; ml[tid][7] = b.w;
    }
    __syncthreads();
    int lane = tid & 63, wid = tid >> 6;
    int tw = wid * 2 + (lane >> 5);
    int l31 = lane & 31;
    uint32_t ow[8];
#pragma unroll
    for (int ti = 0; ti < 8; ++ti) {
        uint32_t m = ml[ti * 32 + l31][tw];
        uint32_t myw = 0;
#pragma unroll
        for (int c = 0; c < 32; ++c) {
            uint64_t bl = __ballot(((m >> c) & 1) != 0);
            uint32_t v = (lane < 32) ? (uint32_t)bl : (uint32_t)(bl >> 32);
            if (l31 == c) myw = v;
        }
        ow[ti] = myw;
    }
    uint32_t* dst = maskT + (size_t)(j0 + tw * 32 + l31) * 128 + bi * 8;
    *reinterpret_cast<uint4*>(dst)     = make_uint4(ow[0], ow[1], ow[2], ow[3]);
    *reinterpret_cast<uint4*>(dst + 4) = make_uint4(ow[4], ow[5], ow[6], ow[7]);
}

// ---------------- initial projection: h = hin @ Wp + bp ----------------
__global__ __launch_bounds__(256) void k_proj(const uint16_t* __restrict__ hin_bf,
                                              const uint16_t* __restrict__ WpT,
                                              const float* __restrict__ bp,
                                              float* __restrict__ h_f32,
                                              uint16_t* __restrict__ hcur_bf) {
    int bx = blockIdx.x, by = blockIdx.y;
    int tid = threadIdx.x, lane = tid & 63, wid = tid >> 6;
    int wr = wid >> 1, wc = wid & 1;
    int l16 = lane & 15, g = lane >> 4;
    int i0 = bx * 64 + wr * 32, d0 = by * 64 + wc * 32;
    f32x4 acc[2][2] = {};
#pragma unroll
    for (int ks = 0; ks < 8; ++ks) {
        int kb = ks * 32 + g * 8;
        bf16x8 afr[2], bfr[2];
#pragma unroll
        for (int mr = 0; mr < 2; ++mr) afr[mr] = ld_frag(hin_bf + (size_t)(i0 + mr * 16 + l16) * 256 + kb);
#pragma unroll
        for (int nr = 0; nr < 2; ++nr) bfr[nr] = ld_frag(WpT + (size_t)(d0 + nr * 16 + l16) * 256 + kb);
#pragma unroll
        for (int mr = 0; mr < 2; ++mr)
#pragma unroll
            for (int nr = 0; nr < 2; ++nr)
                acc[mr][nr] = MFMA(afr[mr], bfr[nr], acc[mr][nr]);
    }
#pragma unroll
    for (int mr = 0; mr < 2; ++mr)
#pragma unroll
        for (int nr = 0; nr < 2; ++nr) {
            int d = d0 + nr * 16 + l16;
            float bias = bp[d];
#pragma unroll
            for (int r = 0; r < 4; ++r) {
                int i = i0 + mr * 16 + g * 4 + r;
                float v = acc[mr][nr][r] + bias;
                h_f32[(size_t)i * 256 + d] = v;
                hcur_bf[(size_t)i * 256 + d] = f2bf(v);
            }
        }
}

// ---------------- fused message+gate GEMM + kk GEMV + qq partials + gate L1; writes gmT ----------------
__global__ __launch_bounds__(256) void k_msgg(const uint16_t* __restrict__ hcur_bf,
                                              const uint16_t* __restrict__ z_bf,
                                              const uint16_t* __restrict__ WmT,
                                              const uint16_t* __restrict__ WgT,
                                              const float* __restrict__ bm,
                                              const float* __restrict__ bg,
                                              const float* __restrict__ wqv,
                                              const float* __restrict__ wkv,
                                              const float* __restrict__ cvec,
                                              uint16_t* __restrict__ gmT,
                                              float* __restrict__ qqp,
                                              float* __restrict__ kkv,
                                              float* __restrict__ gsum,
                                              int layer) {
    __shared__ float wkv_s[256], wqv_s[256];
    __shared__ float wred[4];
    int tid = threadIdx.x;
    wkv_s[tid] = wkv[layer * 256 + tid];
    wqv_s[tid] = wqv[layer * 256 + tid];
    __syncthreads();

    int bx = blockIdx.x, by = blockIdx.y;
    int lane = tid & 63, wid = tid >> 6;
    int wr = wid >> 1, wc = wid & 1;
    int l16 = lane & 15, g = lane >> 4;
    int i0 = bx * 64 + wr * 32, d0 = by * 64 + wc * 32;
    bool doKK = (by == 0);
    const uint16_t* WmTl = WmT + layer * 65536;
    const uint16_t* WgTl = WgT + layer * 98304;
    f32x4 am[2][2] = {}, ag[2][2] = {};
    float kkp[2] = {0.f, 0.f};
#pragma unroll
    for (int ks = 0; ks < 8; ++ks) {
        int kb = ks * 32 + g * 8;
        bf16x8 afr[2], bmf[2], bgf[2];
#pragma unroll
        for (int mr = 0; mr < 2; ++mr) afr[mr] = ld_frag(hcur_bf + (size_t)(i0 + mr * 16 + l16) * 256 + kb);
#pragma unroll
        for (int nr = 0; nr < 2; ++nr) {
            bmf[nr] = ld_frag(WmTl + (size_t)(d0 + nr * 16 + l16) * 256 + kb);
            bgf[nr] = ld_frag(WgTl + (size_t)(d0 + nr * 16 + l16) * 384 + kb);
        }
        if (doKK) {
#pragma unroll
            for (int mr = 0; mr < 2; ++mr)
#pragma unroll
                for (int u = 0; u < 8; ++u)
                    kkp[mr] += bf2f((uint16_t)afr[mr][u]) * wkv_s[kb + u];
        }
#pragma unroll
        for (int mr = 0; mr < 2; ++mr)
#pragma unroll
            for (int nr = 0; nr < 2; ++nr) {
                am[mr][nr] = MFMA(afr[mr], bmf[nr], am[mr][nr]);
                ag[mr][nr] = MFMA(afr[mr], bgf[nr], ag[mr][nr]);
            }
    }
#pragma unroll
    for (int ks = 0; ks < 4; ++ks) {   // z part of concat: k = 256..383
        int kb = ks * 32 + g * 8;
        bf16x8 afr[2], bgf[2];
#pragma unroll
        for (int mr = 0; mr < 2; ++mr) afr[mr] = ld_frag(z_bf + (size_t)(i0 + mr * 16 + l16) * 128 + kb);
#pragma unroll
        for (int nr = 0; nr < 2; ++nr) bgf[nr] = ld_frag(WgTl + (size_t)(d0 + nr * 16 + l16) * 384 + 256 + kb);
#pragma unroll
        for (int mr = 0; mr < 2; ++mr)
#pragma unroll
            for (int nr = 0; nr < 2; ++nr)
                ag[mr][nr] = MFMA(afr[mr], bgf[nr], ag[mr][nr]);
    }
    float gs = 0.f;
    float qqt[2][4] = {};
#pragma unroll
    for (int mr = 0; mr < 2; ++mr)
#pragma unroll
        for (int nr = 0; nr < 2; ++nr) {
            int d = d0 + nr * 16 + l16;
            float bmv = bm[layer * 256 + d], bgv = bg[layer * 256 + d];
            float wqd = wqv_s[d];
            ushort4 pack;
#pragma unroll
            for (int r = 0; r < 4; ++r) {
                float rm = am[mr][nr][r] + bmv; rm = rm > 0.f ? rm : 0.f;
                float gt = 1.f / (1.f + __expf(-(ag[mr][nr][r] + bgv)));
                gs += gt;
                float gmv = gt * rm;
                qqt[mr][r] += gmv * wqd;
                ((uint16_t*)&pack)[r] = f2bf(gmv);
            }
            int i = i0 + mr * 16 + g * 4;
            *reinterpret_cast<ushort4*>(gmT + (size_t)d * cN + i) = pack;
        }
    // deterministic qq partials: slot = by*2 + wc, reduce over 16 l16 lanes
#pragma unroll
    for (int mr = 0; mr < 2; ++mr)
#pragma unroll
        for (int r = 0; r < 4; ++r) {
            float v = qqt[mr][r];
            v += __shfl_xor(v, 1, 64);
            v += __shfl_xor(v, 2, 64);
            v += __shfl_xor(v, 4, 64);
            v += __shfl_xor(v, 8, 64);
            if (l16 == 0) qqp[(size_t)(by * 2 + wc) * cN + i0 + mr * 16 + g * 4 + r] = v;
        }
    if (doKK) {
        float cc = cvec[layer * 2 + 0] + cvec[layer * 2 + 1];
#pragma unroll
        for (int mr = 0; mr < 2; ++mr) {
            float v = kkp[mr];
            v += __shfl_xor(v, 16, 64);
            v += __shfl_xor(v, 32, 64);
            if (lane < 16) kkv[i0 + mr * 16 + l16] = v + cc;
        }
    }
    for (int off = 32; off; off >>= 1) gs += __shfl_down(gs, off, 64);
    if (lane == 0) wred[wid] = gs;
    __syncthreads();
    if (tid == 0) atomicAdd(gsum, wred[0] + wred[1] + wred[2] + wred[3]);
}

// ---------------- per-row: qq = sum of 8 partials ; den = sum_masked exp2(lrelu') ----------------
__global__ __launch_bounds__(256) void k_stats(const float* __restrict__ qqp,
                                               const float* __restrict__ kkv,
                                               const uint32_t* __restrict__ maskw,
                                               float2* __restrict__ stats2) {
    int wid = threadIdx.x >> 6, lane = threadIdx.x & 63;
    int i = blockIdx.x * 4 + wid;
    float qq = 0.f;
#pragma unroll
    for (int s = 0; s < 8; ++s) qq += qqp[(size_t)s * cN + i];
    const uint32_t* mrow = maskw + (size_t)i * 128;
    float den = 0.f;
#pragma unroll 4
    for (int c = 0; c < 64; ++c) {
        int j = c * 64 + lane;
        uint32_t w = mrow[j >> 5];
        bool on = (w >> (j & 31)) & 1;
        float e = qq + kkv[j];
        e = fmaxf(e, 0.01f * e);
        e = fminf(e, 80.f);
        den += on ? exp2f(e) : 0.f;
    }
#pragma unroll
    for (int off = 32; off; off >>= 1) den += __shfl_xor(den, off, 64);
    if (lane == 0) stats2[i] = make_float2(qq, den > 0.f ? 1.f / den : 0.f);
}

// ---------------- agg = attention^T @ gm : A in registers, B tile double-buffered in LDS ----------------
// grid (32 j-blocks of 128, 16 i-segs of 256); 512 threads = 8 waves, wave = 16 j x 256 d.
__global__ __launch_bounds__(512, 4) void k_agg(const uint16_t* __restrict__ gmT,
                                                const float2* __restrict__ stats2,
                                                const uint32_t* __restrict__ maskT,
                                                const float* __restrict__ kkv,
                                                _Float16* __restrict__ part) {
    constexpr int ASTR = 72;                           // elems; 144B row stride, 16B-aligned
    __shared__ uint16_t gm_lds[2][256 * ASTR];         // 2 x 36,864 B
    int jb = blockIdx.x, seg = blockIdx.y;
    int tid = threadIdx.x, lane = tid & 63, wid = tid >> 6;
    int l16 = lane & 15, g = lane >> 4;
    int jt = jb * 128 + wid * 16;
    float kkj = kkv[jt + l16];
    int ib0 = seg * 256;
    f32x4 acc[16] = {};

    // staging: thread -> d-row sd = tid>>1, 32-i half (tid&1); 4x16B stores, XOR-swizzled (T2)
    int sd = tid >> 1;
    int sxor = (sd & 7) << 4;
    int scb0 = (tid & 1) * 64;
    const uint16_t* sgp = gmT + (size_t)sd * cN + ib0 + (tid & 1) * 32;
    uint8_t* srow0 = reinterpret_cast<uint8_t*>(&gm_lds[0][0]) + sd * (ASTR * 2);
    uint8_t* srow1 = reinterpret_cast<uint8_t*>(&gm_lds[1][0]) + sd * (ASTR * 2);
    auto stage_to = [&](uint8_t* srow, const uint16_t* sp) {
        bf16x8 a0 = ld_frag(sp), a1 = ld_frag(sp + 8), a2 = ld_frag(sp + 16), a3 = ld_frag(sp + 24);
        *reinterpret_cast<bf16x8*>(srow + ((scb0 +  0) ^ sxor)) = a0;
        *reinterpret_cast<bf16x8*>(srow + ((scb0 + 16) ^ sxor)) = a1;
        *reinterpret_cast<bf16x8*>(srow + ((scb0 + 32) ^ sxor)) = a2;
        *reinterpret_cast<bf16x8*>(srow + ((scb0 + 48) ^ sxor)) = a3;
    };
    stage_to(srow0, sgp);                              // stage 0 -> buf0
    __syncthreads();
    const uint32_t* mrow = maskT + (size_t)(jt + l16) * 128 + (ib0 >> 5);
    int rxor = (l16 & 7) << 4;                         // read-side xor: row&7 == l16&7 for every nr

    for (int stg = 0; stg < 4; ++stg) {
        if (stg < 3) stage_to((stg & 1) ? srow0 : srow1, sgp + (stg + 1) * 64);  // fill alt buffer
        uint2 mw = *reinterpret_cast<const uint2*>(mrow + stg * 2);
        const uint8_t* cb = reinterpret_cast<const uint8_t*>(&gm_lds[stg & 1][0]);
#pragma unroll
        for (int k = 0; k < 2; ++k) {
            uint32_t mword = k ? mw.y : mw.x;
            const float2* sp = stats2 + ib0 + stg * 64 + k * 32 + g * 8;
            union { bf16x8 v; uint16_t s[8]; } af;
#pragma unroll
            for (int u = 0; u < 8; ++u) {
                float2 st = sp[u];
                float e = st.x + kkj;
                e = fmaxf(e, 0.01f * e);
                e = fminf(e, 80.f);
                float w = exp2f(e) * st.y;
                af.s[u] = ((mword >> (g * 8 + u)) & 1) ? f2bf(w) : (uint16_t)0;
            }
            const uint8_t* bbase = cb + ((k * 64 + g * 16) ^ rxor);
#pragma unroll
            for (int nr = 0; nr < 16; ++nr) {
                bf16x8 bfr = *reinterpret_cast<const bf16x8*>(bbase + (size_t)(nr * 16 + l16) * (ASTR * 2));
                acc[nr] = MFMA(af.v, bfr, acc[nr]);
            }
        }
        __syncthreads();   // reads of cur done; alt writes visible for next stage
    }
    _Float16* pb = part + (size_t)seg * cN * 256;
#pragma unroll
    for (int nr = 0; nr < 16; ++nr) {
        int d = nr * 16 + l16;
#pragma unroll
        for (int r = 0; r < 4; ++r) {
            int jr = jt + g * 4 + r;
            pb[(size_t)jr * 256 + d] = (_Float16)acc[nr][r];
        }
    }
}

// ---------------- residual: h = (sum of 16 f16 parts + h)/2 ----------------
__global__ __launch_bounds__(256) void k_resid(const _Float16* __restrict__ part,
                                               float* __restrict__ h_f32,
                                               uint16_t* __restrict__ hcur_bf,
                                               float* __restrict__ out,
                                               int last) {
    int idx = blockIdx.x * 256 + threadIdx.x;          // float4 index over 1M floats
    float4 acc = reinterpret_cast<float4*>(h_f32)[idx];
#pragma unroll
    for (int p = 0; p < 16; ++p) {
        short4 v = reinterpret_cast<const short4*>(part + (size_t)p * cN * 256)[idx];
        const _Float16* hp = reinterpret_cast<const _Float16*>(&v);
        acc.x += (float)hp[0]; acc.y += (float)hp[1]; acc.z += (float)hp[2]; acc.w += (float)hp[3];
    }
    acc.x *= 0.5f; acc.y *= 0.5f; acc.z *= 0.5f; acc.w *= 0.5f;
    reinterpret_cast<float4*>(h_f32)[idx] = acc;
    ushort4 hb; hb.x = f2bf(acc.x); hb.y = f2bf(acc.y); hb.z = f2bf(acc.z); hb.w = f2bf(acc.w);
    reinterpret_cast<ushort4*>(hcur_bf)[idx] = hb;
    if (last) reinterpret_cast<float4*>(out)[idx] = acc;
}

__global__ void k_fin(const float* __restrict__ gsum, float* __restrict__ out) {
    out[(size_t)cN * cHID] = gsum[0] * (1.f / ((float)(cN * cHID) * (float)cL));
}

// ---------------- host side ----------------
extern "C" void kernel_launch(void* const* d_in, const int* in_sizes, int n_in,
                              void* d_out, int out_size, void* d_ws, size_t ws_size,
                              hipStream_t stream) {
    const float* h   = (const float*)d_in[0];
    const int*   adj = (const int*)d_in[1];
    const float* z   = (const float*)d_in[2];
    const float* Wp  = (const float*)d_in[3];
    const float* bp  = (const float*)d_in[4];
    const float* Wm  = (const float*)d_in[5];
    const float* bm  = (const float*)d_in[6];
    const float* Wg  = (const float*)d_in[7];
    const float* bg  = (const float*)d_in[8];
    const float* Wk  = (const float*)d_in[9];
    const float* bk  = (const float*)d_in[10];
    const float* Wq  = (const float*)d_in[11];
    const float* bq  = (const float*)d_in[12];
    const float* a   = (const float*)d_in[13];
    float* out = (float*)d_out;

    uint8_t* ws = (uint8_t*)d_ws;
    size_t cur = 0;
    auto alloc = [&](size_t bytes) -> uint8_t* {
        uint8_t* p = ws + cur;
        cur = (cur + bytes + 255) & ~(size_t)255;
        return p;
    };
    uint32_t* maskw  = (uint32_t*)alloc((size_t)cN * 128 * 4);
    uint32_t* maskT  = (uint32_t*)alloc((size_t)cN * 128 * 4);
    float*    h_f32  = (float*)   alloc((size_t)cN * 256 * 4);
    uint16_t* hin_bf = (uint16_t*)alloc((size_t)cN * 256 * 2);
    uint16_t* hcur   = (uint16_t*)alloc((size_t)cN * 256 * 2);
    uint16_t* z_bf   = (uint16_t*)alloc((size_t)cN * 128 * 2);
    uint16_t* WpT    = (uint16_t*)alloc(65536 * 2);
    uint16_t* WmT    = (uint16_t*)alloc((size_t)cL * 65536 * 2);
    uint16_t* WgT    = (uint16_t*)alloc((size_t)cL * 98304 * 2);
    uint16_t* gmT    = (uint16_t*)alloc((size_t)cN * 256 * 2);
    float*    wqv    = (float*)   alloc(cL * 256 * 4);
    float*    wkv    = (float*)   alloc(cL * 256 * 4);
    float*    cvec   = (float*)   alloc(256);
    float*    qqp    = (float*)   alloc(8ull * cN * 4);
    float*    kk     = (float*)   alloc(cN * 4);
    float2*   stats2 = (float2*)  alloc(cN * 8);
    float*    gsum   = (float*)   alloc(256);
    _Float16* part   = (_Float16*)alloc(16ull * cN * 256 * 2);
    (void)cur;

    hipMemsetAsync(gsum, 0, 4, stream);

    k_prep<<<1648, 256, 0, stream>>>(h, z, Wp, Wm, Wg, Wq, bq, Wk, bk, a,
                                     hin_bf, z_bf, WpT, WmT, WgT, wqv, wkv, cvec);
    k_bits<<<cN / 4, 256, 0, stream>>>(adj, maskw);
    k_bitsT<<<256, 256, 0, stream>>>(maskw, maskT);
    k_proj<<<dim3(64, 4), 256, 0, stream>>>(hin_bf, WpT, bp, h_f32, hcur);

    for (int l = 0; l < cL; ++l) {
        k_msgg<<<dim3(64, 4), 256, 0, stream>>>(hcur, z_bf, WmT, WgT, bm, bg,
                                                wqv, wkv, cvec, gmT, qqp, kk, gsum, l);
        k_stats<<<cN / 4, 256, 0, stream>>>(qqp, kk, maskw, stats2);
        k_agg<<<dim3(32, 16), 512, 0, stream>>>(gmT, stats2, maskT, kk, part);
        k_resid<<<cN * 256 / 4 / 256, 256, 0, stream>>>(part, h_f32, hcur, out, l == cL - 1 ? 1 : 0);
    }
    k_fin<<<1, 1, 0, stream>>>(gsum, out);
}